// Round 4
// baseline (633.620 us; speedup 1.0000x reference)
//
#include <hip/hip_runtime.h>

typedef unsigned short u16;
typedef _Float16 f16;
typedef __attribute__((ext_vector_type(8))) _Float16 f16x8;   // MFMA A/B operand (4 VGPRs)
typedef __attribute__((ext_vector_type(4))) float f32x4;

__device__ __forceinline__ u16 f2bf(float f) {
  unsigned int u = __builtin_bit_cast(unsigned int, f);
  u += 0x7fffu + ((u >> 16) & 1u);
  return (u16)(u >> 16);
}

#define MFMA16(acc, a, b) acc = __builtin_amdgcn_mfma_f32_16x16x32_f16(a, b, acc, 0, 0, 0)

__device__ __forceinline__ void gl2lds16(const void* g, void* l) {
  __builtin_amdgcn_global_load_lds(
      (const __attribute__((address_space(1))) void*)g,
      (__attribute__((address_space(3))) void*)l, 16, 0, 0);
}

// ---------------------------------------------------------------------------
// f32 -> f16 conversion, 8 elems/thread, vectorized.
// ---------------------------------------------------------------------------
__global__ __launch_bounds__(256) void cvt_f32_f16_k(const float* __restrict__ src, f16* __restrict__ dst,
                                                     int n8) {
  int i = blockIdx.x * 256 + threadIdx.x;
  if (i >= n8) return;
  const float* p = src + (size_t)i * 8;
  f32x4 a = *(const f32x4*)p;
  f32x4 b = *(const f32x4*)(p + 4);
  f16x8 o;
#pragma unroll
  for (int j = 0; j < 4; j++) {
    o[j] = (f16)a[j];
    o[j + 4] = (f16)b[j];
  }
  *(f16x8*)(dst + (size_t)i * 8) = o;
}

// ---------------------------------------------------------------------------
// GEMM: C[M,N] = A[M,K] @ W[N,K]^T + bias[N]; f16 in, f32 accum.
// EPI 0: f32 out[row*N+col]   (final output)
// EPI 1: f16 out[((row>>10)*16 + (col>>6))*65536 + (row&1023)*64 + (col&63)]  ([B,H,L,64])
// ---------------------------------------------------------------------------
template <int EPI>
__global__ __launch_bounds__(256) void gemm_bt(const f16* __restrict__ A, const f16* __restrict__ Wt,
                                               const float* __restrict__ bias, void* __restrict__ outv,
                                               int M, int N, int K, float scale) {
  const int nbn = N >> 7;
  int id = blockIdx.x;
  int m0 = (id / nbn) << 7;
  int n0 = (id % nbn) << 7;
  int tid = threadIdx.x;
  int w = tid >> 6, lane = tid & 63, c = lane & 15, g = lane >> 4;
  int wm = (w >> 1) << 6, wn = (w & 1) << 6;

  __shared__ f16 As[128 * 32];
  __shared__ f16 Bs[128 * 32];

  f32x4 acc[4][4] = {};
  int ci0 = tid, ci1 = tid + 256;

  for (int k0 = 0; k0 < K; k0 += 32) {
    __syncthreads();
    gl2lds16(A + (size_t)(m0 + (ci0 >> 2)) * K + k0 + ((ci0 & 3) << 3), As + w * 512);
    gl2lds16(A + (size_t)(m0 + (ci1 >> 2)) * K + k0 + ((ci1 & 3) << 3), As + w * 512 + 2048);
    gl2lds16(Wt + (size_t)(n0 + (ci0 >> 2)) * K + k0 + ((ci0 & 3) << 3), Bs + w * 512);
    gl2lds16(Wt + (size_t)(n0 + (ci1 >> 2)) * K + k0 + ((ci1 & 3) << 3), Bs + w * 512 + 2048);
    __syncthreads();
    f16x8 af[4], bf[4];
#pragma unroll
    for (int mf = 0; mf < 4; mf++) af[mf] = *(const f16x8*)(As + ((wm + mf * 16 + c) << 5) + (g << 3));
#pragma unroll
    for (int nf = 0; nf < 4; nf++) bf[nf] = *(const f16x8*)(Bs + ((wn + nf * 16 + c) << 5) + (g << 3));
#pragma unroll
    for (int mf = 0; mf < 4; mf++)
#pragma unroll
      for (int nf = 0; nf < 4; nf++) MFMA16(acc[mf][nf], af[mf], bf[nf]);
  }

#pragma unroll
  for (int mf = 0; mf < 4; mf++)
#pragma unroll
    for (int nf = 0; nf < 4; nf++)
#pragma unroll
      for (int r = 0; r < 4; r++) {
        int row = m0 + wm + mf * 16 + (g << 2) + r;
        int col = n0 + wn + nf * 16 + c;
        float v = (acc[mf][nf][r] + bias[col]) * scale;
        if (EPI == 0) {
          ((float*)outv)[(size_t)row * N + col] = v;
        } else {
          size_t idx = (size_t)((row >> 10) * 16 + (col >> 6)) * 65536 + ((row & 1023) << 6) + (col & 63);
          ((u16*)outv)[idx] = __builtin_bit_cast(u16, (f16)v);
        }
      }
}

// ---------------------------------------------------------------------------
// Scores + softmax. One block per (b,h, 16-row q-tile). 4 waves, each owns a
// 256-wide k-chunk; full 1024-score row lives in registers (16 frags/lane).
// Adds rel-key term via a 16x65 qrel tile (MFMA vs rel_emb) in LDS.
// Writes normalized f32 attn (into d_out) + clipped-bucket sums (t=0 / t=64).
// ---------------------------------------------------------------------------
__global__ __launch_bounds__(256) void attn_sm(const f16* __restrict__ Q, const f16* __restrict__ Km,
                                               const f16* __restrict__ rel, float* __restrict__ attn,
                                               float* __restrict__ arel0, float* __restrict__ arel64) {
  int id = blockIdx.x;
  int sw = ((id & 7) << 10) + (id >> 3);  // XCD-bijective swizzle (8192 % 8 == 0)
  int bh = sw >> 6;
  int q0 = (sw & 63) << 4;
  int tid = threadIdx.x;
  int w = tid >> 6, lane = tid & 63, c = lane & 15, g = lane >> 4;

  __shared__ float qrel_s[16 * 68];
  __shared__ float rmax[4][16], rsum[4][16], rlo[4][16], rhi[4][16];

  const f16* Qb = Q + ((size_t)bh << 16);
  const f16* Kb = Km + ((size_t)bh << 16);

  f16x8 aq0 = *(const f16x8*)(Qb + ((q0 + c) << 6) + (g << 3));
  f16x8 aq1 = *(const f16x8*)(Qb + ((q0 + c) << 6) + 32 + (g << 3));

  if (w == 0) {  // qrel[q,t] = Q[q,:] . rel_emb[t,:]
#pragma unroll
    for (int tf = 0; tf < 5; tf++) {
      int t = tf * 16 + c;
      int tc = (t < 65) ? t : 0;
      f32x4 ar = {};
      f16x8 b0 = *(const f16x8*)(rel + (tc << 6) + (g << 3));
      f16x8 b1 = *(const f16x8*)(rel + (tc << 6) + 32 + (g << 3));
      MFMA16(ar, aq0, b0);
      MFMA16(ar, aq1, b1);
      if (t < 65) {
#pragma unroll
        for (int r = 0; r < 4; r++) qrel_s[((g << 2) + r) * 68 + t] = ar[r];
      }
    }
  }
  __syncthreads();

  float s[16][4];
  int kbase = w << 8;
#pragma unroll
  for (int f = 0; f < 16; f++) {
    int kcol = kbase + (f << 4) + c;
    f32x4 a4 = {};
    f16x8 b0 = *(const f16x8*)(Kb + (kcol << 6) + (g << 3));
    f16x8 b1 = *(const f16x8*)(Kb + (kcol << 6) + 32 + (g << 3));
    MFMA16(a4, aq0, b0);
    MFMA16(a4, aq1, b1);
#pragma unroll
    for (int r = 0; r < 4; r++) {
      int rowl = (g << 2) + r;
      int d = kcol - (q0 + rowl);
      int t = (d < -32 ? -32 : (d > 32 ? 32 : d)) + 32;
      s[f][r] = a4[r] + qrel_s[rowl * 68 + t];
    }
  }

  float m[4] = {-3.0e38f, -3.0e38f, -3.0e38f, -3.0e38f};
#pragma unroll
  for (int f = 0; f < 16; f++)
#pragma unroll
    for (int r = 0; r < 4; r++) m[r] = fmaxf(m[r], s[f][r]);
#pragma unroll
  for (int mk = 1; mk <= 8; mk <<= 1)
#pragma unroll
    for (int r = 0; r < 4; r++) m[r] = fmaxf(m[r], __shfl_xor(m[r], mk, 64));
  if (c == 0) {
#pragma unroll
    for (int r = 0; r < 4; r++) rmax[w][(g << 2) + r] = m[r];
  }
  __syncthreads();
  float gm[4];
#pragma unroll
  for (int r = 0; r < 4; r++) {
    int rowl = (g << 2) + r;
    gm[r] = fmaxf(fmaxf(rmax[0][rowl], rmax[1][rowl]), fmaxf(rmax[2][rowl], rmax[3][rowl]));
  }
  float sum[4] = {0, 0, 0, 0}, lo[4] = {0, 0, 0, 0}, hi[4] = {0, 0, 0, 0};
#pragma unroll
  for (int f = 0; f < 16; f++)
#pragma unroll
    for (int r = 0; r < 4; r++) {
      float p = __expf(s[f][r] - gm[r]);
      s[f][r] = p;
      sum[r] += p;
      int d = (kbase + (f << 4) + c) - (q0 + (g << 2) + r);
      if (d <= -32) lo[r] += p;
      if (d >= 32) hi[r] += p;
    }
#pragma unroll
  for (int mk = 1; mk <= 8; mk <<= 1)
#pragma unroll
    for (int r = 0; r < 4; r++) {
      sum[r] += __shfl_xor(sum[r], mk, 64);
      lo[r] += __shfl_xor(lo[r], mk, 64);
      hi[r] += __shfl_xor(hi[r], mk, 64);
    }
  if (c == 0) {
#pragma unroll
    for (int r = 0; r < 4; r++) {
      int rowl = (g << 2) + r;
      rsum[w][rowl] = sum[r];
      rlo[w][rowl] = lo[r];
      rhi[w][rowl] = hi[r];
    }
  }
  __syncthreads();
  float inv[4];
#pragma unroll
  for (int r = 0; r < 4; r++) {
    int rowl = (g << 2) + r;
    float tot = rsum[0][rowl] + rsum[1][rowl] + rsum[2][rowl] + rsum[3][rowl];
    inv[r] = 1.0f / tot;
  }
  if (w == 0 && c == 0) {
#pragma unroll
    for (int r = 0; r < 4; r++) {
      int rowl = (g << 2) + r;
      float l4 = rlo[0][rowl] + rlo[1][rowl] + rlo[2][rowl] + rlo[3][rowl];
      float h4 = rhi[0][rowl] + rhi[1][rowl] + rhi[2][rowl] + rhi[3][rowl];
      arel0[bh * 1024 + q0 + rowl] = l4 * inv[r];
      arel64[bh * 1024 + q0 + rowl] = h4 * inv[r];
    }
  }
  float* ab = attn + ((size_t)bh << 20);
#pragma unroll
  for (int f = 0; f < 16; f++)
#pragma unroll
    for (int r = 0; r < 4; r++) {
      size_t idx = ((size_t)(q0 + (g << 2) + r) << 10) | (size_t)(kbase + (f << 4) + c);
      ab[idx] = s[f][r] * inv[r];
    }
}

// ---------------------------------------------------------------------------
// ctx = attn @ V + rel-value term; block = (b,h) x 128 q-rows, 4 waves x 32 rows.
// attn read back as f32 -> f16 frags; V transposed through LDS per 32-k step.
// Rel-value epilogue: band (63 diag attn values) + two clipped-bucket sums.
// Writes ctx as [B, L, H*64] f16.
// ---------------------------------------------------------------------------
__global__ __launch_bounds__(256) void ctx_pv(const float* __restrict__ attn, const f16* __restrict__ V,
                                              const f16* __restrict__ rel, const float* __restrict__ arel0,
                                              const float* __restrict__ arel64, f16* __restrict__ ctx) {
  int id = blockIdx.x;
  int sw = ((id & 7) << 7) + (id >> 3);  // 1024 % 8 == 0
  int bh = sw >> 3;
  int q0 = (sw & 7) << 7;
  int b = bh >> 4, h = bh & 15;
  int tid = threadIdx.x;
  int w = tid >> 6, lane = tid & 63, c = lane & 15, g = lane >> 4;

  __shared__ f16 VT[64][40];  // V^T tile, row stride 80 B (16B-aligned)
  __shared__ f16 rel_s[65 * 64];
  __shared__ float band[128][65];  // attn[q][q-31..q+31]
  __shared__ float a0s[128], a64s[128];

  const float* ab = attn + ((size_t)bh << 20);
  const f16* Vb = V + ((size_t)bh << 16);

  for (int i = tid; i < 65 * 64; i += 256) rel_s[i] = rel[i];
  for (int i = tid; i < 128; i += 256) {
    a0s[i] = arel0[bh * 1024 + q0 + i];
    a64s[i] = arel64[bh * 1024 + q0 + i];
  }
  for (int i = tid; i < 128 * 64; i += 256) {
    int qr = i >> 6, tp = i & 63;
    if (tp < 63) {
      int k = q0 + qr - 31 + tp;
      band[qr][tp] = (k >= 0 && k < 1024) ? ab[((size_t)(q0 + qr) << 10) + k] : 0.0f;
    }
  }

  f32x4 acc[2][4] = {};

  for (int k0 = 0; k0 < 1024; k0 += 32) {
    __syncthreads();
    {
      int kr = tid >> 3, e0 = (tid & 7) << 3;
      f16x8 vv = *(const f16x8*)(Vb + ((size_t)(k0 + kr) << 6) + e0);
#pragma unroll
      for (int j = 0; j < 8; j++) VT[e0 + j][kr] = vv[j];
    }
    __syncthreads();
    f16x8 aA[2], bV[4];
#pragma unroll
    for (int mf = 0; mf < 2; mf++) {
      const float* ap = ab + (((size_t)(q0 + (w << 5) + mf * 16 + c)) << 10) + k0 + (g << 3);
      f32x4 r0 = *(const f32x4*)ap;
      f32x4 r1 = *(const f32x4*)(ap + 4);
#pragma unroll
      for (int j = 0; j < 4; j++) {
        aA[mf][j] = (f16)r0[j];
        aA[mf][j + 4] = (f16)r1[j];
      }
    }
#pragma unroll
    for (int nf = 0; nf < 4; nf++) bV[nf] = *(const f16x8*)(&VT[nf * 16 + c][g << 3]);
#pragma unroll
    for (int mf = 0; mf < 2; mf++)
#pragma unroll
      for (int nf = 0; nf < 4; nf++) MFMA16(acc[mf][nf], aA[mf], bV[nf]);
  }

  // rel-value contributions: t=0 & t=64 buckets + diagonal band (t=1..63)
#pragma unroll
  for (int mf = 0; mf < 2; mf++)
#pragma unroll
    for (int r = 0; r < 4; r++) {
      int qr = (w << 5) + mf * 16 + (g << 2) + r;
      float c0 = a0s[qr], c64 = a64s[qr];
#pragma unroll
      for (int nf = 0; nf < 4; nf++) {
        int col = nf * 16 + c;
        acc[mf][nf][r] += c0 * (float)rel_s[col] + c64 * (float)rel_s[64 * 64 + col];
      }
    }
  for (int t = 1; t < 64; t++) {
    float rv[4];
#pragma unroll
    for (int nf = 0; nf < 4; nf++) rv[nf] = (float)rel_s[t * 64 + nf * 16 + c];
#pragma unroll
    for (int mf = 0; mf < 2; mf++)
#pragma unroll
      for (int r = 0; r < 4; r++) {
        float bc = band[(w << 5) + mf * 16 + (g << 2) + r][t - 1];
#pragma unroll
        for (int nf = 0; nf < 4; nf++) acc[mf][nf][r] += bc * rv[nf];
      }
  }

#pragma unroll
  for (int mf = 0; mf < 2; mf++)
#pragma unroll
    for (int nf = 0; nf < 4; nf++)
#pragma unroll
      for (int r = 0; r < 4; r++) {
        int qr = (w << 5) + mf * 16 + (g << 2) + r;
        int col = nf * 16 + c;
        ctx[(((size_t)(b << 10) + (size_t)(q0 + qr)) << 10) + (h << 6) + col] = (f16)acc[mf][nf][r];
      }
}

extern "C" void kernel_launch(void* const* d_in, const int* in_sizes, int n_in, void* d_out, int out_size,
                              void* d_ws, size_t ws_size, hipStream_t stream) {
  const float* key = (const float*)d_in[0];
  const float* value = (const float*)d_in[1];
  const float* query = (const float*)d_in[2];
  const float* Wq = (const float*)d_in[3];
  const float* bq = (const float*)d_in[4];
  const float* Wk = (const float*)d_in[5];
  const float* bk = (const float*)d_in[6];
  const float* Wv = (const float*)d_in[7];
  const float* bv = (const float*)d_in[8];
  const float* Wo = (const float*)d_in[9];
  const float* bo = (const float*)d_in[10];
  const float* rel = (const float*)d_in[11];

  char* ws = (char*)d_ws;
  f16* Xf = (f16*)(ws);                  // 16 MB staging (query/key/value f16, reused)
  f16* Qw = (f16*)(ws + (16u << 20));    // 16 MB: Q proj; later ctx
  f16* Kw = (f16*)(ws + (32u << 20));    // 16 MB: K proj; later V proj
  f16* Wf0 = (f16*)(ws + (48u << 20));   // Wq f16, 2 MB
  f16* Wf1 = (f16*)(ws + (50u << 20));   // Wk
  f16* Wf2 = (f16*)(ws + (52u << 20));   // Wv
  f16* Wf3 = (f16*)(ws + (54u << 20));   // Wo
  f16* relf = (f16*)(ws + (56u << 20));  // 8320 B
  float* a0 = (float*)(ws + (56u << 20) + (1u << 16));
  float* a64 = (float*)(ws + (56u << 20) + (1u << 16) + (1u << 19));

  float* outp = (float*)d_out;
  float* attnp = outp + (size_t)8 * 1024 * 1024;  // attn (f32) starts at elem 8388608

  dim3 blk(256);
  const int n8x = (8 * 1024 * 1024) / 8;
  const int n8w = (1024 * 1024) / 8;
  const int n8r = (65 * 64) / 8;

  cvt_f32_f16_k<<<n8w / 256, blk, 0, stream>>>(Wq, Wf0, n8w);
  cvt_f32_f16_k<<<n8w / 256, blk, 0, stream>>>(Wk, Wf1, n8w);
  cvt_f32_f16_k<<<n8w / 256, blk, 0, stream>>>(Wv, Wf2, n8w);
  cvt_f32_f16_k<<<n8w / 256, blk, 0, stream>>>(Wo, Wf3, n8w);
  cvt_f32_f16_k<<<(n8r + 255) / 256, blk, 0, stream>>>(rel, relf, n8r);

  cvt_f32_f16_k<<<n8x / 256, blk, 0, stream>>>(query, Xf, n8x);
  gemm_bt<1><<<512, blk, 0, stream>>>(Xf, Wf0, bq, Qw, 8192, 1024, 1024, 0.125f);
  cvt_f32_f16_k<<<n8x / 256, blk, 0, stream>>>(key, Xf, n8x);
  gemm_bt<1><<<512, blk, 0, stream>>>(Xf, Wf1, bk, Kw, 8192, 1024, 1024, 1.0f);

  attn_sm<<<8192, blk, 0, stream>>>(Qw, Kw, relf, attnp, a0, a64);

  cvt_f32_f16_k<<<n8x / 256, blk, 0, stream>>>(value, Xf, n8x);
  gemm_bt<1><<<512, blk, 0, stream>>>(Xf, Wf2, bv, Kw, 8192, 1024, 1024, 1.0f);  // V -> old K region

  ctx_pv<<<1024, blk, 0, stream>>>(attnp, Kw, relf, a0, a64, Qw);  // ctx -> old Q region

  gemm_bt<0><<<512, blk, 0, stream>>>(Qw, Wf3, bo, outp, 8192, 1024, 1024, 1.0f);
}